// Round 1
// baseline (362.437 us; speedup 1.0000x reference)
//
#include <hip/hip_runtime.h>

// HemorrhageNet: per-row Poisson-binomial count distribution over 96 probs,
// truncated at 5, binned to severity[5] = {c0, c1+c2, c3+c4, c5, 0}.
//
// R3 strategy: ONE THREAD PER ROW — no cross-lane combine at all.
//  - The previous (R2) kernel split a row across 8 lanes and merged partial
//    distributions with 3 dependent rounds of 6 __shfl_xor (ds_bpermute,
//    ~120 cyc latency each). rocprof showed it latency-bound: HBM 22%,
//    VALUBusy 33%, occupancy 67% -- nothing saturated.
//  - Here each thread streams its row's 96 probs (24 float4 loads; the 8
//    consecutive float4s per array cover the full cache lines, so the 128B
//    lane stride costs nothing extra at HBM).
//  - Cheaper recurrence: a_k += p*(a_{k-1} - a_k)  (2 ops/coeff, no q),
//    a0 = fma(-p, a0, a0). a5 is never tracked: mass conservation gives
//    c5 = 1 - sum(a0..a4) (same trick R2 used in the butterfly).
//    => 9 VALU ops/prob vs ~20 effective before; zero ds ops, zero lgkm
//    dependencies. VALU issue floor ~11 us, memory floor ~55-80 us.
//  - __launch_bounds__(256,4): ~128 VGPR budget so all 24 loads can be
//    hoisted in flight (24 KB/wave outstanding -- deep queue beats wave
//    count for a streaming kernel).

#define THREADS 256

__global__ __launch_bounds__(THREADS, 4) void hemorrhage_kernel(
    const float* __restrict__ x1,
    const float* __restrict__ x2,
    const float* __restrict__ x3,
    float* __restrict__ out)
{
    const int row = blockIdx.x * THREADS + threadIdx.x;

    const float4* __restrict__ r1 = (const float4*)(x1 + (size_t)row * 32);
    const float4* __restrict__ r2 = (const float4*)(x2 + (size_t)row * 32);
    const float4* __restrict__ r3 = (const float4*)(x3 + (size_t)row * 32);

    // ---- issue all 24 loads; compiler keeps them in flight (VGPR cap 128) ----
    float4 v[24];
#pragma unroll
    for (int j = 0; j < 8; ++j) v[j] = r1[j];
#pragma unroll
    for (int j = 0; j < 8; ++j) v[8 + j] = r2[j];
#pragma unroll
    for (int j = 0; j < 8; ++j) v[16 + j] = r3[j];

    // ---- truncated (deg<=4) Poisson-binomial recurrence, 9 ops/prob ----
    float a0 = 1.0f, a1 = 0.0f, a2 = 0.0f, a3 = 0.0f, a4 = 0.0f;

#define STEP(P)                              \
    do {                                     \
        const float p_ = (P);                \
        a4 = fmaf(p_, a3 - a4, a4);          \
        a3 = fmaf(p_, a2 - a3, a3);          \
        a2 = fmaf(p_, a1 - a2, a2);          \
        a1 = fmaf(p_, a0 - a1, a1);          \
        a0 = fmaf(-p_, a0, a0);              \
    } while (0)

#pragma unroll
    for (int j = 0; j < 24; ++j) {
        STEP(v[j].x);
        STEP(v[j].y);
        STEP(v[j].z);
        STEP(v[j].w);
    }
#undef STEP

    // ---- severity bins; c5 via mass conservation (sum of dist == 1) ----
    const float c5 = 1.0f - (((a0 + a1) + (a2 + a3)) + a4);

    float* __restrict__ o = out + (size_t)row * 5;
    o[0] = a0;
    o[1] = a1 + a2;
    o[2] = a3 + a4;
    o[3] = c5;
    o[4] = 0.0f;   // out is re-poisoned: must write zeros
}

extern "C" void kernel_launch(void* const* d_in, const int* in_sizes, int n_in,
                              void* d_out, int out_size, void* d_ws, size_t ws_size,
                              hipStream_t stream) {
    const float* x1 = (const float*)d_in[0];
    const float* x2 = (const float*)d_in[1];
    const float* x3 = (const float*)d_in[2];
    float* out = (float*)d_out;

    const int rows = in_sizes[0] / 32;        // 1048576
    const int blocks = rows / THREADS;        // 4096 (exact)
    hemorrhage_kernel<<<blocks, THREADS, 0, stream>>>(x1, x2, x3, out);
}

// Round 4
// 354.696 us; speedup vs baseline: 1.0218x; 1.0218x over previous
//
#include <hip/hip_runtime.h>

// HemorrhageNet: per-row Poisson-binomial count distribution over 96 probs,
// truncated at 5, binned to severity[5] = {c0, c1+c2, c3+c4, c5, 0}.
//
// R4 strategy: LDS-staged, ONE THREAD PER ROW.  (Resubmitted unchanged —
// rounds 2 and 3 both died to broker/container infrastructure, this kernel
// has never actually run.)
//  - R2 (8 lanes/row + 3 shuffle rounds): coalesced loads but latency-bound
//    on dependent ds_bpermute chains (126 us, VALUBusy 33%).
//  - R3 (thread-per-row direct loads): no cross-lane work, but 128-B lane
//    stride broke the coalescer -- 64 line-requests per load instr, ~8x the
//    L1 request rate; compiler also sank loads (VGPR=32, nothing in flight).
//    139 us, VALUBusy 20%, HBM 21%: request-rate bound.
//  - R4 gets both halves right:
//      * global loads fully coalesced: thread t loads float4 (t + 128j) of
//        the block's 16 KB array chunk (8 lines/instr, full merge);
//      * staged into LDS [128][33] (pad +1 word): read bank = (t+k)%32,
//        2-way aliasing only == free (m136); write pattern also <=2-way;
//      * each thread then streams its own 32 floats/phase from LDS:
//        zero cross-lane dependencies, 9 VALU ops/prob.
//  - 3 phases (x1,x2,x3), single 16.9 KB buffer -> 9 blocks/CU = 18 waves/CU
//    of independent barrier domains (stall coverage via TLP).
//  - Prologue loads x1+x2 to regs; x3 prefetched during phase-0 compute, so
//    every ds_write's vmcnt wait is short or fully hidden.
//  - VALU floor ~15 us; memory floor ~40-55 us -> memory-bound target.

#define THREADS 128
#define ROWS_PER_BLOCK 128
#define STRIDE 33   // LDS words per row: +1 pad -> 2-way bank aliasing (free)

__global__ __launch_bounds__(THREADS, 4) void hemorrhage_kernel(
    const float* __restrict__ x1,
    const float* __restrict__ x2,
    const float* __restrict__ x3,
    float* __restrict__ out)
{
    __shared__ float lds[ROWS_PER_BLOCK * STRIDE];

    const int t = threadIdx.x;
    const size_t blockBase = (size_t)blockIdx.x * ROWS_PER_BLOCK * 32;  // floats

    const float4* __restrict__ g1 = (const float4*)(x1 + blockBase);
    const float4* __restrict__ g2 = (const float4*)(x2 + blockBase);
    const float4* __restrict__ g3 = (const float4*)(x3 + blockBase);

    // ---- prologue: coalesced loads of x1 and x2 chunks into registers ----
    float4 v[8], w[8];
#pragma unroll
    for (int j = 0; j < 8; ++j) v[j] = g1[t + THREADS * j];
#pragma unroll
    for (int j = 0; j < 8; ++j) w[j] = g2[t + THREADS * j];

    float a0 = 1.0f, a1 = 0.0f, a2 = 0.0f, a3 = 0.0f, a4 = 0.0f;

    // float4 f = t + 128j  ->  row r = f>>3, col4 c = f&7; padded LDS word
    // r*33 + 4c + i.  Write banks: (16j + r' + 4c + i) mod 32, r' in 0..7 ->
    // max 2-way. Read banks: (t+k) mod 32 -> 2-way. Both free.
#define WRITE_LDS(SRC)                                        \
    _Pragma("unroll")                                         \
    for (int j = 0; j < 8; ++j) {                             \
        const int f_ = t + THREADS * j;                       \
        float* wp_ = &lds[(f_ >> 3) * STRIDE + (f_ & 7) * 4]; \
        wp_[0] = (SRC)[j].x; wp_[1] = (SRC)[j].y;             \
        wp_[2] = (SRC)[j].z; wp_[3] = (SRC)[j].w;             \
    }

    // truncated (deg<=4) Poisson-binomial step: 9 VALU ops/prob
#define STEP(P)                              \
    do {                                     \
        const float p_ = (P);                \
        a4 = fmaf(p_, a3 - a4, a4);          \
        a3 = fmaf(p_, a2 - a3, a3);          \
        a2 = fmaf(p_, a1 - a2, a2);          \
        a1 = fmaf(p_, a0 - a1, a1);          \
        a0 = fmaf(-p_, a0, a0);              \
    } while (0)

#define COMPUTE32()                                           \
    _Pragma("unroll")                                         \
    for (int k = 0; k < 32; ++k) STEP(lds[t * STRIDE + k]);

    // ---- phase 0: x1 ----
    WRITE_LDS(v);
    __syncthreads();
#pragma unroll
    for (int j = 0; j < 8; ++j) v[j] = g3[t + THREADS * j];  // prefetch x3
    COMPUTE32();
    __syncthreads();

    // ---- phase 1: x2 (loads long since landed) ----
    WRITE_LDS(w);
    __syncthreads();
    COMPUTE32();
    __syncthreads();

    // ---- phase 2: x3 (issued one full compute phase ago) ----
    WRITE_LDS(v);
    __syncthreads();
    COMPUTE32();

#undef COMPUTE32
#undef STEP
#undef WRITE_LDS

    // ---- severity bins; c5 via mass conservation (dist sums to 1) ----
    const float c5 = 1.0f - (((a0 + a1) + (a2 + a3)) + a4);

    float* __restrict__ o = out + (size_t)(blockIdx.x * ROWS_PER_BLOCK + t) * 5;
    o[0] = a0;
    o[1] = a1 + a2;
    o[2] = a3 + a4;
    o[3] = c5;
    o[4] = 0.0f;   // out is re-poisoned: must write zeros
}

extern "C" void kernel_launch(void* const* d_in, const int* in_sizes, int n_in,
                              void* d_out, int out_size, void* d_ws, size_t ws_size,
                              hipStream_t stream) {
    const float* x1 = (const float*)d_in[0];
    const float* x2 = (const float*)d_in[1];
    const float* x3 = (const float*)d_in[2];
    float* out = (float*)d_out;

    const int rows = in_sizes[0] / 32;                 // 1048576
    const int blocks = rows / ROWS_PER_BLOCK;          // 8192 (exact)
    hemorrhage_kernel<<<blocks, THREADS, 0, stream>>>(x1, x2, x3, out);
}